// Round 4
// baseline (975.058 us; speedup 1.0000x reference)
//
#include <hip/hip_runtime.h>
#include <hip/hip_bf16.h>
#include <stdint.h>

typedef int v4i __attribute__((ext_vector_type(4)));

#define DEVI static __device__ __forceinline__

DEVI void gload16(const void* g, void* l) {
    __builtin_amdgcn_global_load_lds(
        (const __attribute__((address_space(1))) void*)g,
        (__attribute__((address_space(3))) void*)l,
        16, 0, 0);
}

#define WAITV(n) asm volatile("s_waitcnt vmcnt(" #n ")" ::: "memory")
#define SBAR()   __builtin_amdgcn_s_barrier()

// ---------------------------------------------------------------------------
// Prep: elementwise binarize fp32 -> int8 (+1 / -1), 16 elems per thread
// ---------------------------------------------------------------------------
__global__ __launch_bounds__(256) void k_bin_f32_to_i8(
    const float* __restrict__ w, int8_t* __restrict__ o, int n16)
{
    int t = blockIdx.x * 256 + threadIdx.x;
    if (t >= n16) return;
    const float4* s = (const float4*)w + (size_t)t * 4;
    union { int4 v; int8_t b[16]; } u;
#pragma unroll
    for (int i = 0; i < 4; ++i) {
        float4 f = s[i];
        u.b[i*4+0] = (f.x >= 0.f) ? (int8_t)1 : (int8_t)-1;
        u.b[i*4+1] = (f.y >= 0.f) ? (int8_t)1 : (int8_t)-1;
        u.b[i*4+2] = (f.z >= 0.f) ? (int8_t)1 : (int8_t)-1;
        u.b[i*4+3] = (f.w >= 0.f) ? (int8_t)1 : (int8_t)-1;
    }
    *(int4*)(o + (size_t)t * 16) = u.v;
}

// x [16384,784] fp32 -> A0 [16384,768] int8
__global__ __launch_bounds__(256) void k_bin_x(
    const float* __restrict__ x, int8_t* __restrict__ o)
{
    int t = blockIdx.x * 256 + threadIdx.x;
    int row = t / 48;
    int ch  = t % 48;
    const float4* s = (const float4*)(x + (size_t)row * 784 + ch * 16);
    union { int4 v; int8_t b[16]; } u;
#pragma unroll
    for (int i = 0; i < 4; ++i) {
        float4 f = s[i];
        u.b[i*4+0] = (f.x >= 0.f) ? (int8_t)1 : (int8_t)-1;
        u.b[i*4+1] = (f.y >= 0.f) ? (int8_t)1 : (int8_t)-1;
        u.b[i*4+2] = (f.z >= 0.f) ? (int8_t)1 : (int8_t)-1;
        u.b[i*4+3] = (f.w >= 0.f) ? (int8_t)1 : (int8_t)-1;
    }
    *(int4*)(o + (size_t)row * 768 + ch * 16) = u.v;
}

// ---------------------------------------------------------------------------
// Binary GEMM, 128x128 tile, 4 waves (2Mx2N, 64x64 each), BK=64B, 4-deep
// LDS ring (64 KB total -> 2 blocks/CU, independent barrier domains for
// anti-phase LDS/MFMA overlap). Stage distance 3, counted WAITV(4),
// ping-pong fragment registers (no copies). Swizzle: slot ^= (row>>1)&3.
// Fused exact column stats in epilogue.
// ---------------------------------------------------------------------------
__global__ __launch_bounds__(256, 2)
void k_gemm(const int8_t* __restrict__ A, const int8_t* __restrict__ B,
            int16_t* __restrict__ C, int* __restrict__ gsum,
            unsigned long long* __restrict__ gsq,
            int N, int K, int nbx)
{
    __shared__ __align__(16) int8_t lds[65536]; // A ring 4x8KB | B ring 4x8KB

    const int tid  = threadIdx.x;
    const int lane = tid & 63;
    const int wave = tid >> 6;

    // T1: bijective XCD swizzle (gridDim.x % 8 == 0)
    const int cpx = gridDim.x >> 3;
    const int id  = blockIdx.x;
    const int sw  = (id & 7) * cpx + (id >> 3);
    const int bx  = sw % nbx;
    const int by  = sw / nbx;

    const int NT = K >> 6;

    // staging: thread t -> LDS row sr=t>>2 (per 64-row half), phys slot t&3.
    // phys slot p of row r holds logical slot p ^ ((r>>1)&3); pre-swizzle src.
    const int sr  = tid >> 2;
    const int asw = (((tid & 3) ^ ((sr >> 1) & 3)) << 4);
    const int8_t* gA0 = A + (size_t)(by * 128 + sr)      * K + asw;
    const int8_t* gA1 = A + (size_t)(by * 128 + 64 + sr) * K + asw;
    const int8_t* gB0 = B + (size_t)(bx * 128 + sr)      * K + asw;
    const int8_t* gB1 = B + (size_t)(bx * 128 + 64 + sr) * K + asw;
    const int ldw = wave << 10;   // wave-uniform dest (+lane*16 implicit)

    // fragments: logical slot ksl of row (16m+lrow) at phys ksl^((lrow>>1)&3)
    const int lrow = lane & 15;
    const int ksl  = lane >> 4;
    const int wr = (wave >> 1) * 64;
    const int wc = (wave & 1) * 64;
    const int fsw = ((ksl ^ ((lrow >> 1) & 3)) << 4);
    int aoff[4], boff[4];
#pragma unroll
    for (int m = 0; m < 4; ++m) aoff[m] = ((wr + m * 16 + lrow) << 6) + fsw;
#pragma unroll
    for (int n = 0; n < 4; ++n) boff[n] = ((wc + n * 16 + lrow) << 6) + fsw;

    v4i acc[4][4];
    v4i zero = {0, 0, 0, 0};
#pragma unroll
    for (int m = 0; m < 4; ++m)
#pragma unroll
        for (int n = 0; n < 4; ++n) acc[m][n] = zero;

#define STAGE(kt) do { const int _o = (kt) << 6; const int _b = ((kt) & 3) << 13; \
        gload16(gA0 + _o, lds + _b + ldw);                                        \
        gload16(gA1 + _o, lds + _b + 4096 + ldw);                                 \
        gload16(gB0 + _o, lds + 32768 + _b + ldw);                                \
        gload16(gB1 + _o, lds + 32768 + _b + 4096 + ldw); } while (0)

#define READF(da, db, slot) do {                                                  \
        const int8_t* _ab = lds + ((slot) << 13);                                 \
        const int8_t* _bb = lds + 32768 + ((slot) << 13);                         \
        _Pragma("unroll") for (int m = 0; m < 4; ++m)                             \
            da[m] = *(const v4i*)(_ab + aoff[m]);                                 \
        _Pragma("unroll") for (int n = 0; n < 4; ++n)                             \
            db[n] = *(const v4i*)(_bb + boff[n]); } while (0)

#define MFMA16(fa, fb) do {                                                       \
        __builtin_amdgcn_s_setprio(1);                                            \
        _Pragma("unroll") for (int m = 0; m < 4; ++m)                             \
        _Pragma("unroll") for (int n = 0; n < 4; ++n)                             \
            acc[m][n] = __builtin_amdgcn_mfma_i32_16x16x64_i8(                    \
                fa[m], fb[n], acc[m][n], 0, 0, 0);                                \
        __builtin_amdgcn_s_setprio(0); } while (0)

#define TILE(kt, ca, cb, na, nb) do {                                             \
        if ((kt) + 3 < NT) STAGE((kt) + 3);                                       \
        if ((kt) < NT - 3)       { WAITV(4); }                                    \
        else if ((kt) == NT - 3) { WAITV(0); }                                    \
        if ((kt) + 1 < NT) READF(na, nb, ((kt) + 1) & 3);                         \
        MFMA16(ca, cb);                                                           \
        SBAR(); } while (0)

    // prologue: tiles 0,1,2 in flight; drain 0,1 (leave tile 2's 4 loads)
    STAGE(0); STAGE(1); STAGE(2);
    WAITV(4);
    SBAR();

    v4i aX[4], bX[4], aY[4], bY[4];
    READF(aX, bX, 0);

    for (int kt2 = 0; kt2 < NT; kt2 += 2) {
        TILE(kt2,     aX, bX, aY, bY);
        TILE(kt2 + 1, aY, bY, aX, bX);
    }
#undef STAGE
#undef READF
#undef MFMA16
#undef TILE

    // ---- epilogue: C write (i16) + fused exact column stats ----
    const int row0 = by * 128 + wr + ksl * 4;
    const int col0 = bx * 128 + wc + lrow;
#pragma unroll
    for (int m = 0; m < 4; ++m)
#pragma unroll
        for (int rr = 0; rr < 4; ++rr) {
            int16_t* dst = C + (size_t)(row0 + m * 16 + rr) * N + col0;
#pragma unroll
            for (int n = 0; n < 4; ++n)
                dst[n * 16] = (int16_t)acc[m][n][rr];
        }
#pragma unroll
    for (int n = 0; n < 4; ++n) {
        int s = 0; unsigned q = 0;
#pragma unroll
        for (int m = 0; m < 4; ++m)
#pragma unroll
            for (int rr = 0; rr < 4; ++rr) {
                int v = acc[m][n][rr];
                s += v;
                q += (unsigned)(v * v);
            }
        s += __shfl_xor(s, 16);
        s += __shfl_xor(s, 32);
        q += (unsigned)__shfl_xor((int)q, 16);
        q += (unsigned)__shfl_xor((int)q, 32);
        if (ksl == 0) {
            const int col = col0 + n * 16;
            atomicAdd(&gsum[col], s);
            atomicAdd(&gsq[col], (unsigned long long)q);
        }
    }
}

// ---------------------------------------------------------------------------
// Layer-4 split-K GEMM: C4[16384,16](i32, atomic) = A @ W4p[16,4096]^T
// ---------------------------------------------------------------------------
__global__ __launch_bounds__(256)
void k_gemm4(const int8_t* __restrict__ A, const int8_t* __restrict__ Bw,
             int* __restrict__ C4, int K)
{
    const int lane = threadIdx.x & 63;
    const int wave = threadIdx.x >> 6;
    const int lrow = lane & 15, ksl = lane >> 4;
    const int r0 = blockIdx.x * 128 + wave * 32;
    const int k0 = blockIdx.y * 512;

    const int8_t* ap0 = A + (size_t)(r0 + lrow) * K + k0 + ksl * 16;
    const int8_t* ap1 = ap0 + (size_t)16 * K;
    const int8_t* bp  = Bw + (size_t)lrow * K + k0 + ksl * 16;

    v4i acc0 = {0,0,0,0}, acc1 = {0,0,0,0};
#pragma unroll
    for (int kk = 0; kk < 8; ++kk) {
        v4i a0 = *(const v4i*)(ap0 + kk * 64);
        v4i a1 = *(const v4i*)(ap1 + kk * 64);
        v4i b  = *(const v4i*)(bp  + kk * 64);
        acc0 = __builtin_amdgcn_mfma_i32_16x16x64_i8(a0, b, acc0, 0, 0, 0);
        acc1 = __builtin_amdgcn_mfma_i32_16x16x64_i8(a1, b, acc1, 0, 0, 0);
    }
#pragma unroll
    for (int rr = 0; rr < 4; ++rr) {
        atomicAdd(&C4[(size_t)(r0 + ksl * 4 + rr) * 16 + lrow], acc0[rr]);
        atomicAdd(&C4[(size_t)(r0 + 16 + ksl * 4 + rr) * 16 + lrow], acc1[rr]);
    }
}

// stats for the 16-col (10 active) layer-4 output, int32 input
__global__ __launch_bounds__(256)
void k_colstats4(const int* __restrict__ C4, int rows,
                 int* __restrict__ gsum, unsigned long long* __restrict__ gsq)
{
    const int col = threadIdx.x & 15, grp = threadIdx.x >> 4;
    const int rpb = rows / gridDim.x;
    const int r0  = blockIdx.x * rpb;
    int s = 0; unsigned long long q = 0;
    for (int r = grp; r < rpb; r += 16) {
        int v = C4[(size_t)(r0 + r) * 16 + col];
        s += v;
        q += (unsigned long long)((long long)v * (long long)v);
    }
    __shared__ int ss[256];
    __shared__ unsigned long long sq[256];
    ss[threadIdx.x] = s; sq[threadIdx.x] = q;
    __syncthreads();
    if (grp == 0) {
#pragma unroll
        for (int t = 1; t < 16; ++t) { s += ss[t * 16 + col]; q += sq[t * 16 + col]; }
        atomicAdd(&gsum[col], s);
        atomicAdd(&gsq[col], q);
    }
}

// bn fold: pa = rsqrt(var+eps)*gamma ; pb = beta - mu*rsqrt*gamma
__global__ __launch_bounds__(128)
void k_finalize(const int* __restrict__ gsum, const unsigned long long* __restrict__ gsq,
                const float* __restrict__ gamma, const float* __restrict__ beta,
                float* __restrict__ pa, float* __restrict__ pb,
                int rows, int ncols_act, int ncols_pad)
{
    int c = blockIdx.x * 128 + threadIdx.x;
    if (c >= ncols_pad) return;
    double mu  = (double)gsum[c] / (double)rows;
    double var = (double)(long long)gsq[c] / (double)rows - mu * mu;
    float rs = rsqrtf((float)var + 1e-5f);
    float g  = (c < ncols_act) ? gamma[c] : 0.f;
    float be = (c < ncols_act) ? beta[c]  : 0.f;
    pa[c] = rs * g;
    pb[c] = be - (float)mu * rs * g;
}

// bn + binarize: A_next = sign(C*pa + pb), 16 elems/thread
__global__ __launch_bounds__(256)
void k_bnbin(const int16_t* __restrict__ C, const float* __restrict__ pa,
             const float* __restrict__ pb, int8_t* __restrict__ Aout,
             int n16, int colmask)
{
    int t = blockIdx.x * 256 + threadIdx.x;
    if (t >= n16) return;
    const size_t base = (size_t)t * 16;
    const int c0 = (int)(base & (size_t)colmask);
    union { int4 v; short s[8]; } u0, u1;
    u0.v = *(const int4*)(C + base);
    u1.v = *(const int4*)(C + base + 8);
    float4 a[4], b[4];
#pragma unroll
    for (int i = 0; i < 4; ++i) {
        a[i] = *(const float4*)(pa + c0 + i * 4);
        b[i] = *(const float4*)(pb + c0 + i * 4);
    }
    union { int4 v; int8_t b[16]; } o;
#pragma unroll
    for (int i = 0; i < 16; ++i) {
        float y = (float)((i < 8) ? u0.s[i] : u1.s[i - 8]);
        float aa = ((const float*)&a[i >> 2])[i & 3];
        float bb = ((const float*)&b[i >> 2])[i & 3];
        o.b[i] = (y * aa + bb >= 0.f) ? (int8_t)1 : (int8_t)-1;
    }
    *(int4*)(Aout + base) = o.v;
}

// final: bn4 + log_softmax over 10 classes (C4 int32, stride 16)
__global__ __launch_bounds__(256)
void k_logsoftmax(const int* __restrict__ C4, const float* __restrict__ pa,
                  const float* __restrict__ pb, float* __restrict__ out, int rows)
{
    int r = blockIdx.x * 256 + threadIdx.x;
    if (r >= rows) return;
    const int* row = C4 + (size_t)r * 16;
    float v[10];
    float m = -1e30f;
#pragma unroll
    for (int c = 0; c < 10; ++c) {
        v[c] = (float)row[c] * pa[c] + pb[c];
        m = fmaxf(m, v[c]);
    }
    float s = 0.f;
#pragma unroll
    for (int c = 0; c < 10; ++c) s += expf(v[c] - m);
    float ls = logf(s);
#pragma unroll
    for (int c = 0; c < 10; ++c) out[(size_t)r * 10 + c] = v[c] - m - ls;
}

// ---------------------------------------------------------------------------
extern "C" void kernel_launch(void* const* d_in, const int* in_sizes, int n_in,
                              void* d_out, int out_size, void* d_ws, size_t ws_size,
                              hipStream_t stream)
{
    (void)in_sizes; (void)n_in; (void)out_size; (void)ws_size;
    const float* x  = (const float*)d_in[0];
    const float* w1 = (const float*)d_in[1];
    const float* w2 = (const float*)d_in[2];
    const float* w3 = (const float*)d_in[3];
    const float* w4 = (const float*)d_in[4];
    const float* g1 = (const float*)d_in[5];
    const float* b1 = (const float*)d_in[6];
    const float* g2 = (const float*)d_in[7];
    const float* b2 = (const float*)d_in[8];
    const float* g3 = (const float*)d_in[9];
    const float* b3 = (const float*)d_in[10];
    const float* g4 = (const float*)d_in[11];
    const float* b4 = (const float*)d_in[12];
    float* out = (float*)d_out;

    const int B = 16384, HID = 4096, IND = 768;

    char* p = (char*)d_ws;
    size_t off = 0;
    auto alloc = [&](size_t sz) -> char* {
        char* r = p + off;
        off += (sz + 255) & ~(size_t)255;
        return r;
    };
    int8_t*  W1   = (int8_t*)alloc((size_t)HID * IND);
    int8_t*  W2   = (int8_t*)alloc((size_t)HID * HID);
    int8_t*  W3   = (int8_t*)alloc((size_t)HID * HID);
    int8_t*  W4p  = (int8_t*)alloc((size_t)16 * HID);
    int8_t*  Abuf = (int8_t*)alloc((size_t)B * HID);
    int16_t* C    = (int16_t*)alloc((size_t)B * HID * 2);
    int*     C4   = (int*)alloc((size_t)B * 16 * 4);
    int*     gsum = (int*)alloc((size_t)HID * 4);
    unsigned long long* gsq = (unsigned long long*)alloc((size_t)HID * 8);
    float*   pa   = (float*)alloc((size_t)HID * 4);
    float*   pb   = (float*)alloc((size_t)HID * 4);

    // ---- prep ----
    hipMemsetAsync(W4p, 0, (size_t)16 * HID, stream);
    k_bin_f32_to_i8<<<(HID * IND / 16 + 255) / 256, 256, 0, stream>>>(w1, W1, HID * IND / 16);
    k_bin_f32_to_i8<<<(HID * HID / 16 + 255) / 256, 256, 0, stream>>>(w2, W2, HID * HID / 16);
    k_bin_f32_to_i8<<<(HID * HID / 16 + 255) / 256, 256, 0, stream>>>(w3, W3, HID * HID / 16);
    k_bin_f32_to_i8<<<(10 * HID / 16 + 255) / 256, 256, 0, stream>>>(w4, W4p, 10 * HID / 16);
    k_bin_x<<<B * 48 / 256, 256, 0, stream>>>(x, Abuf);

    const int nbx = HID / 128, nby = B / 128;   // 32 x 128 = 4096 blocks (%8==0)

    // ---- layer 1 ----
    hipMemsetAsync(gsum, 0, HID * 12, stream);
    k_gemm<<<nbx * nby, 256, 0, stream>>>(Abuf, W1, C, gsum, gsq, HID, IND, nbx);
    k_finalize<<<HID / 128, 128, 0, stream>>>(gsum, gsq, g1, b1, pa, pb, B, HID, HID);
    k_bnbin<<<B * HID / 16 / 256, 256, 0, stream>>>(C, pa, pb, Abuf, B * HID / 16, HID - 1);

    // ---- layer 2 ----
    hipMemsetAsync(gsum, 0, HID * 12, stream);
    k_gemm<<<nbx * nby, 256, 0, stream>>>(Abuf, W2, C, gsum, gsq, HID, HID, nbx);
    k_finalize<<<HID / 128, 128, 0, stream>>>(gsum, gsq, g2, b2, pa, pb, B, HID, HID);
    k_bnbin<<<B * HID / 16 / 256, 256, 0, stream>>>(C, pa, pb, Abuf, B * HID / 16, HID - 1);

    // ---- layer 3 ----
    hipMemsetAsync(gsum, 0, HID * 12, stream);
    k_gemm<<<nbx * nby, 256, 0, stream>>>(Abuf, W3, C, gsum, gsq, HID, HID, nbx);
    k_finalize<<<HID / 128, 128, 0, stream>>>(gsum, gsq, g3, b3, pa, pb, B, HID, HID);
    k_bnbin<<<B * HID / 16 / 256, 256, 0, stream>>>(C, pa, pb, Abuf, B * HID / 16, HID - 1);

    // ---- layer 4 (split-K, int32 atomics) ----
    hipMemsetAsync(C4, 0, (size_t)B * 16 * 4, stream);
    k_gemm4<<<dim3(B / 128, 8), 256, 0, stream>>>(Abuf, W4p, C4, HID);
    hipMemsetAsync(gsum, 0, HID * 12, stream);
    k_colstats4<<<16, 256, 0, stream>>>(C4, B, gsum, gsq);
    k_finalize<<<1, 128, 0, stream>>>(gsum, gsq, g4, b4, pa, pb, B, 10, 16);
    k_logsoftmax<<<B / 256, 256, 0, stream>>>(C4, pa, pb, out, B);
}

// Round 5
// 803.771 us; speedup vs baseline: 1.2131x; 1.2131x over previous
//
#include <hip/hip_runtime.h>
#include <hip/hip_bf16.h>
#include <stdint.h>

typedef int v4i __attribute__((ext_vector_type(4)));

#define DEVI static __device__ __forceinline__

DEVI void gload16(const void* g, void* l) {
    __builtin_amdgcn_global_load_lds(
        (const __attribute__((address_space(1))) void*)g,
        (__attribute__((address_space(3))) void*)l,
        16, 0, 0);
}

#define WAITV(n) asm volatile("s_waitcnt vmcnt(" #n ")" ::: "memory")
#define SBAR()   __builtin_amdgcn_s_barrier()

// ---------------------------------------------------------------------------
// Prep: elementwise binarize fp32 -> int8 (+1 / -1), 16 elems per thread
// ---------------------------------------------------------------------------
__global__ __launch_bounds__(256) void k_bin_f32_to_i8(
    const float* __restrict__ w, int8_t* __restrict__ o, int n16)
{
    int t = blockIdx.x * 256 + threadIdx.x;
    if (t >= n16) return;
    const float4* s = (const float4*)w + (size_t)t * 4;
    union { int4 v; int8_t b[16]; } u;
#pragma unroll
    for (int i = 0; i < 4; ++i) {
        float4 f = s[i];
        u.b[i*4+0] = (f.x >= 0.f) ? (int8_t)1 : (int8_t)-1;
        u.b[i*4+1] = (f.y >= 0.f) ? (int8_t)1 : (int8_t)-1;
        u.b[i*4+2] = (f.z >= 0.f) ? (int8_t)1 : (int8_t)-1;
        u.b[i*4+3] = (f.w >= 0.f) ? (int8_t)1 : (int8_t)-1;
    }
    *(int4*)(o + (size_t)t * 16) = u.v;
}

// x [16384,784] fp32 -> A0 [16384,768] int8
__global__ __launch_bounds__(256) void k_bin_x(
    const float* __restrict__ x, int8_t* __restrict__ o)
{
    int t = blockIdx.x * 256 + threadIdx.x;
    int row = t / 48;
    int ch  = t % 48;
    const float4* s = (const float4*)(x + (size_t)row * 784 + ch * 16);
    union { int4 v; int8_t b[16]; } u;
#pragma unroll
    for (int i = 0; i < 4; ++i) {
        float4 f = s[i];
        u.b[i*4+0] = (f.x >= 0.f) ? (int8_t)1 : (int8_t)-1;
        u.b[i*4+1] = (f.y >= 0.f) ? (int8_t)1 : (int8_t)-1;
        u.b[i*4+2] = (f.z >= 0.f) ? (int8_t)1 : (int8_t)-1;
        u.b[i*4+3] = (f.w >= 0.f) ? (int8_t)1 : (int8_t)-1;
    }
    *(int4*)(o + (size_t)row * 768 + ch * 16) = u.v;
}

// ---------------------------------------------------------------------------
// Binary GEMM, 256x256 tile, 8 waves (2Mx4N), BK=64B, 4-deep LDS ring.
// Two phases per K-tile, each {stage-half + ds_reads + barrier + 16 MFMA
// (setprio) + barrier}: next-phase reads stay in flight under the MFMA
// cluster via compiler-counted lgkmcnt (m201 structure). Per-tile WAITV(4)
// drains 2 tiles ahead of fragment reads (barrier in between -> race-free).
// Swizzle: slot ^= (row>>1)&3 (conflict-free). Fused column stats.
// ---------------------------------------------------------------------------
__global__ __launch_bounds__(512, 2)
void k_gemm256(const int8_t* __restrict__ A, const int8_t* __restrict__ B,
               int16_t* __restrict__ C, int* __restrict__ gsum,
               unsigned long long* __restrict__ gsq,
               int N, int K, int nbx)
{
    __shared__ __align__(16) int8_t lds[131072]; // A ring 4x16KB | B ring 4x16KB

    const int tid  = threadIdx.x;
    const int lane = tid & 63;
    const int wave = tid >> 6;

    // T1: bijective XCD swizzle (gridDim.x % 8 == 0)
    const int cpx = gridDim.x >> 3;
    const int id  = blockIdx.x;
    const int sw  = (id & 7) * cpx + (id >> 3);
    const int bx  = sw % nbx;
    const int by  = sw / nbx;

    const int NT = K >> 6;

    // staging: thread t -> LDS row sr=t>>2, phys 16B slot t&3.
    // phys slot p of row r holds logical slot p ^ ((r>>1)&3); pre-swizzle src.
    const int sr  = tid >> 2;
    const int asw = (((tid & 3) ^ ((sr >> 1) & 3)) << 4);
    const int8_t* gA0 = A + (size_t)(by * 256 + sr)       * K + asw;
    const int8_t* gA1 = A + (size_t)(by * 256 + 128 + sr) * K + asw;
    const int8_t* gB0 = B + (size_t)(bx * 256 + sr)       * K + asw;
    const int8_t* gB1 = B + (size_t)(bx * 256 + 128 + sr) * K + asw;
    const int ld0 = (wave * 64) << 4;
    const int ld1 = (512 + wave * 64) << 4;

    // fragments: logical slot ksl of row (16m+lrow) at phys ksl^((lrow>>1)&3)
    const int lrow = lane & 15;
    const int ksl  = lane >> 4;
    const int wr = (wave >> 2) * 128;
    const int wc = (wave & 3) * 64;
    const int fsw = ((ksl ^ ((lrow >> 1) & 3)) << 4);
    int aoff[8], boff[4];
#pragma unroll
    for (int m = 0; m < 8; ++m) aoff[m] = ((wr + m * 16 + lrow) << 6) + fsw;
#pragma unroll
    for (int n = 0; n < 4; ++n) boff[n] = ((wc + n * 16 + lrow) << 6) + fsw;

    v4i acc[8][4];
    v4i zero = {0, 0, 0, 0};
#pragma unroll
    for (int m = 0; m < 8; ++m)
#pragma unroll
        for (int n = 0; n < 4; ++n) acc[m][n] = zero;

#define STAGE_A(kt) do { const int _o = (kt) << 6; const int _b = ((kt) & 3) * 16384; \
        gload16(gA0 + _o, lds + _b + ld0); gload16(gA1 + _o, lds + _b + ld1); } while (0)
#define STAGE_B(kt) do { const int _o = (kt) << 6; const int _b = ((kt) & 3) * 16384; \
        gload16(gB0 + _o, lds + 65536 + _b + ld0); gload16(gB1 + _o, lds + 65536 + _b + ld1); } while (0)

#define READF(da, db, slot) do {                                                  \
        const int8_t* _ab = lds + ((slot) * 16384);                               \
        const int8_t* _bb = lds + 65536 + ((slot) * 16384);                       \
        _Pragma("unroll") for (int m = 0; m < 4; ++m)                             \
            da[m] = *(const v4i*)(_ab + aoff[m]);                                 \
        _Pragma("unroll") for (int n = 0; n < 4; ++n)                             \
            db[n] = *(const v4i*)(_bb + boff[n]); } while (0)

// full pipelined K-tile: phase0 {stageA(kt+3), read ag, bar, MFMA(CA,CB), bar}
//                        phase1 {stageB(kt+3), vmcnt, read next(NA,NB), bar,
//                                MFMA(ag,CB) [lgkmcnt(8) via dep], bar}
#define TILEF(kt, CA, CB, NA, NB) do {                                            \
        const int8_t* _ab = lds + (((kt) & 3) * 16384);                           \
        if ((kt) + 3 < NT) STAGE_A((kt) + 3);                                     \
        v4i _ag[4];                                                               \
        _Pragma("unroll") for (int m = 0; m < 4; ++m)                             \
            _ag[m] = *(const v4i*)(_ab + aoff[4 + m]);                            \
        SBAR();                                                                   \
        __builtin_amdgcn_s_setprio(1);                                            \
        _Pragma("unroll") for (int m = 0; m < 4; ++m)                             \
        _Pragma("unroll") for (int n = 0; n < 4; ++n)                             \
            acc[m][n] = __builtin_amdgcn_mfma_i32_16x16x64_i8(                    \
                CA[m], CB[n], acc[m][n], 0, 0, 0);                                \
        __builtin_amdgcn_s_setprio(0);                                            \
        SBAR();                                                                   \
        if ((kt) + 3 < NT) STAGE_B((kt) + 3);                                     \
        if ((kt) < NT - 3)       { WAITV(4); }                                    \
        else if ((kt) == NT - 3) { WAITV(0); }                                    \
        READF(NA, NB, ((kt) + 1) & 3);                                            \
        SBAR();                                                                   \
        __builtin_amdgcn_s_setprio(1);                                            \
        _Pragma("unroll") for (int m = 0; m < 4; ++m)                             \
        _Pragma("unroll") for (int n = 0; n < 4; ++n)                             \
            acc[4 + m][n] = __builtin_amdgcn_mfma_i32_16x16x64_i8(                \
                _ag[m], CB[n], acc[4 + m][n], 0, 0, 0);                           \
        __builtin_amdgcn_s_setprio(0);                                            \
        SBAR(); } while (0)

    // prologue: stage tiles 0,1,2 (12 loads); drain tiles 0,1; barrier
    STAGE_A(0); STAGE_B(0);
    STAGE_A(1); STAGE_B(1);
    STAGE_A(2); STAGE_B(2);
    WAITV(4);
    SBAR();

    v4i aX[4], bX[4], aY[4], bY[4];
    READF(aX, bX, 0);

    // main: tiles 0..NT-3 in pairs (NT even), then tile NT-2, then tail NT-1
    for (int kt = 0; kt < NT - 2; kt += 2) {
        TILEF(kt,     aX, bX, aY, bY);
        TILEF(kt + 1, aY, bY, aX, bX);
    }
    TILEF(NT - 2, aX, bX, aY, bY);
    {
        const int8_t* _ab = lds + (((NT - 1) & 3) * 16384);
        v4i ag[4];
#pragma unroll
        for (int m = 0; m < 4; ++m) ag[m] = *(const v4i*)(_ab + aoff[4 + m]);
        __builtin_amdgcn_s_setprio(1);
#pragma unroll
        for (int m = 0; m < 4; ++m)
#pragma unroll
            for (int n = 0; n < 4; ++n)
                acc[m][n] = __builtin_amdgcn_mfma_i32_16x16x64_i8(
                    aY[m], bY[n], acc[m][n], 0, 0, 0);
#pragma unroll
        for (int m = 0; m < 4; ++m)
#pragma unroll
            for (int n = 0; n < 4; ++n)
                acc[4 + m][n] = __builtin_amdgcn_mfma_i32_16x16x64_i8(
                    ag[m], bY[n], acc[4 + m][n], 0, 0, 0);
        __builtin_amdgcn_s_setprio(0);
    }
#undef STAGE_A
#undef STAGE_B
#undef READF
#undef TILEF

    // ---- epilogue: C write (i16) + fused exact column stats ----
    const int row0 = by * 256 + wr + ksl * 4;
    const int col0 = bx * 256 + wc + lrow;
#pragma unroll
    for (int m = 0; m < 8; ++m)
#pragma unroll
        for (int rr = 0; rr < 4; ++rr) {
            int16_t* dst = C + (size_t)(row0 + m * 16 + rr) * N + col0;
#pragma unroll
            for (int n = 0; n < 4; ++n)
                dst[n * 16] = (int16_t)acc[m][n][rr];
        }
#pragma unroll
    for (int n = 0; n < 4; ++n) {
        int s = 0; unsigned q = 0;
#pragma unroll
        for (int m = 0; m < 8; ++m)
#pragma unroll
            for (int rr = 0; rr < 4; ++rr) {
                int v = acc[m][n][rr];
                s += v;
                q += (unsigned)(v * v);
            }
        s += __shfl_xor(s, 16);
        s += __shfl_xor(s, 32);
        q += (unsigned)__shfl_xor((int)q, 16);
        q += (unsigned)__shfl_xor((int)q, 32);
        if (ksl == 0) {
            const int col = col0 + n * 16;
            atomicAdd(&gsum[col], s);
            atomicAdd(&gsq[col], (unsigned long long)q);
        }
    }
}

// ---------------------------------------------------------------------------
// Layer-4 split-K GEMM: C4[16384,16](i32, atomic) = A @ W4p[16,4096]^T
// ---------------------------------------------------------------------------
__global__ __launch_bounds__(256)
void k_gemm4(const int8_t* __restrict__ A, const int8_t* __restrict__ Bw,
             int* __restrict__ C4, int K)
{
    const int lane = threadIdx.x & 63;
    const int wave = threadIdx.x >> 6;
    const int lrow = lane & 15, ksl = lane >> 4;
    const int r0 = blockIdx.x * 128 + wave * 32;
    const int k0 = blockIdx.y * 512;

    const int8_t* ap0 = A + (size_t)(r0 + lrow) * K + k0 + ksl * 16;
    const int8_t* ap1 = ap0 + (size_t)16 * K;
    const int8_t* bp  = Bw + (size_t)lrow * K + k0 + ksl * 16;

    v4i acc0 = {0,0,0,0}, acc1 = {0,0,0,0};
#pragma unroll
    for (int kk = 0; kk < 8; ++kk) {
        v4i a0 = *(const v4i*)(ap0 + kk * 64);
        v4i a1 = *(const v4i*)(ap1 + kk * 64);
        v4i b  = *(const v4i*)(bp  + kk * 64);
        acc0 = __builtin_amdgcn_mfma_i32_16x16x64_i8(a0, b, acc0, 0, 0, 0);
        acc1 = __builtin_amdgcn_mfma_i32_16x16x64_i8(a1, b, acc1, 0, 0, 0);
    }
#pragma unroll
    for (int rr = 0; rr < 4; ++rr) {
        atomicAdd(&C4[(size_t)(r0 + ksl * 4 + rr) * 16 + lrow], acc0[rr]);
        atomicAdd(&C4[(size_t)(r0 + 16 + ksl * 4 + rr) * 16 + lrow], acc1[rr]);
    }
}

// stats for the 16-col (10 active) layer-4 output, int32 input
__global__ __launch_bounds__(256)
void k_colstats4(const int* __restrict__ C4, int rows,
                 int* __restrict__ gsum, unsigned long long* __restrict__ gsq)
{
    const int col = threadIdx.x & 15, grp = threadIdx.x >> 4;
    const int rpb = rows / gridDim.x;
    const int r0  = blockIdx.x * rpb;
    int s = 0; unsigned long long q = 0;
    for (int r = grp; r < rpb; r += 16) {
        int v = C4[(size_t)(r0 + r) * 16 + col];
        s += v;
        q += (unsigned long long)((long long)v * (long long)v);
    }
    __shared__ int ss[256];
    __shared__ unsigned long long sq[256];
    ss[threadIdx.x] = s; sq[threadIdx.x] = q;
    __syncthreads();
    if (grp == 0) {
#pragma unroll
        for (int t = 1; t < 16; ++t) { s += ss[t * 16 + col]; q += sq[t * 16 + col]; }
        atomicAdd(&gsum[col], s);
        atomicAdd(&gsq[col], q);
    }
}

// bn fold: pa = rsqrt(var+eps)*gamma ; pb = beta - mu*rsqrt*gamma
__global__ __launch_bounds__(128)
void k_finalize(const int* __restrict__ gsum, const unsigned long long* __restrict__ gsq,
                const float* __restrict__ gamma, const float* __restrict__ beta,
                float* __restrict__ pa, float* __restrict__ pb,
                int rows, int ncols_act, int ncols_pad)
{
    int c = blockIdx.x * 128 + threadIdx.x;
    if (c >= ncols_pad) return;
    double mu  = (double)gsum[c] / (double)rows;
    double var = (double)(long long)gsq[c] / (double)rows - mu * mu;
    float rs = rsqrtf((float)var + 1e-5f);
    float g  = (c < ncols_act) ? gamma[c] : 0.f;
    float be = (c < ncols_act) ? beta[c]  : 0.f;
    pa[c] = rs * g;
    pb[c] = be - (float)mu * rs * g;
}

// bn + binarize: A_next = sign(C*pa + pb), 16 elems/thread
__global__ __launch_bounds__(256)
void k_bnbin(const int16_t* __restrict__ C, const float* __restrict__ pa,
             const float* __restrict__ pb, int8_t* __restrict__ Aout,
             int n16, int colmask)
{
    int t = blockIdx.x * 256 + threadIdx.x;
    if (t >= n16) return;
    const size_t base = (size_t)t * 16;
    const int c0 = (int)(base & (size_t)colmask);
    union { int4 v; short s[8]; } u0, u1;
    u0.v = *(const int4*)(C + base);
    u1.v = *(const int4*)(C + base + 8);
    float4 a[4], b[4];
#pragma unroll
    for (int i = 0; i < 4; ++i) {
        a[i] = *(const float4*)(pa + c0 + i * 4);
        b[i] = *(const float4*)(pb + c0 + i * 4);
    }
    union { int4 v; int8_t b[16]; } o;
#pragma unroll
    for (int i = 0; i < 16; ++i) {
        float y = (float)((i < 8) ? u0.s[i] : u1.s[i - 8]);
        float aa = ((const float*)&a[i >> 2])[i & 3];
        float bb = ((const float*)&b[i >> 2])[i & 3];
        o.b[i] = (y * aa + bb >= 0.f) ? (int8_t)1 : (int8_t)-1;
    }
    *(int4*)(Aout + base) = o.v;
}

// final: bn4 + log_softmax over 10 classes (C4 int32, stride 16)
__global__ __launch_bounds__(256)
void k_logsoftmax(const int* __restrict__ C4, const float* __restrict__ pa,
                  const float* __restrict__ pb, float* __restrict__ out, int rows)
{
    int r = blockIdx.x * 256 + threadIdx.x;
    if (r >= rows) return;
    const int* row = C4 + (size_t)r * 16;
    float v[10];
    float m = -1e30f;
#pragma unroll
    for (int c = 0; c < 10; ++c) {
        v[c] = (float)row[c] * pa[c] + pb[c];
        m = fmaxf(m, v[c]);
    }
    float s = 0.f;
#pragma unroll
    for (int c = 0; c < 10; ++c) s += expf(v[c] - m);
    float ls = logf(s);
#pragma unroll
    for (int c = 0; c < 10; ++c) out[(size_t)r * 10 + c] = v[c] - m - ls;
}

// ---------------------------------------------------------------------------
extern "C" void kernel_launch(void* const* d_in, const int* in_sizes, int n_in,
                              void* d_out, int out_size, void* d_ws, size_t ws_size,
                              hipStream_t stream)
{
    (void)in_sizes; (void)n_in; (void)out_size; (void)ws_size;
    const float* x  = (const float*)d_in[0];
    const float* w1 = (const float*)d_in[1];
    const float* w2 = (const float*)d_in[2];
    const float* w3 = (const float*)d_in[3];
    const float* w4 = (const float*)d_in[4];
    const float* g1 = (const float*)d_in[5];
    const float* b1 = (const float*)d_in[6];
    const float* g2 = (const float*)d_in[7];
    const float* b2 = (const float*)d_in[8];
    const float* g3 = (const float*)d_in[9];
    const float* b3 = (const float*)d_in[10];
    const float* g4 = (const float*)d_in[11];
    const float* b4 = (const float*)d_in[12];
    float* out = (float*)d_out;

    const int B = 16384, HID = 4096, IND = 768;

    char* p = (char*)d_ws;
    size_t off = 0;
    auto alloc = [&](size_t sz) -> char* {
        char* r = p + off;
        off += (sz + 255) & ~(size_t)255;
        return r;
    };
    int8_t*  W1   = (int8_t*)alloc((size_t)HID * IND);
    int8_t*  W2   = (int8_t*)alloc((size_t)HID * HID);
    int8_t*  W3   = (int8_t*)alloc((size_t)HID * HID);
    int8_t*  W4p  = (int8_t*)alloc((size_t)16 * HID);
    int8_t*  Abuf = (int8_t*)alloc((size_t)B * HID);
    int16_t* C    = (int16_t*)alloc((size_t)B * HID * 2);
    int*     C4   = (int*)alloc((size_t)B * 16 * 4);
    int*     gsum = (int*)alloc((size_t)HID * 4);
    unsigned long long* gsq = (unsigned long long*)alloc((size_t)HID * 8);
    float*   pa   = (float*)alloc((size_t)HID * 4);
    float*   pb   = (float*)alloc((size_t)HID * 4);

    // ---- prep ----
    hipMemsetAsync(W4p, 0, (size_t)16 * HID, stream);
    k_bin_f32_to_i8<<<(HID * IND / 16 + 255) / 256, 256, 0, stream>>>(w1, W1, HID * IND / 16);
    k_bin_f32_to_i8<<<(HID * HID / 16 + 255) / 256, 256, 0, stream>>>(w2, W2, HID * HID / 16);
    k_bin_f32_to_i8<<<(HID * HID / 16 + 255) / 256, 256, 0, stream>>>(w3, W3, HID * HID / 16);
    k_bin_f32_to_i8<<<(10 * HID / 16 + 255) / 256, 256, 0, stream>>>(w4, W4p, 10 * HID / 16);
    k_bin_x<<<B * 48 / 256, 256, 0, stream>>>(x, Abuf);

    const int nbx = HID / 256, nby = B / 256;   // 16 x 64 = 1024 blocks (%8==0)

    // ---- layer 1 ----
    hipMemsetAsync(gsum, 0, HID * 12, stream);
    k_gemm256<<<nbx * nby, 512, 0, stream>>>(Abuf, W1, C, gsum, gsq, HID, IND, nbx);
    k_finalize<<<HID / 128, 128, 0, stream>>>(gsum, gsq, g1, b1, pa, pb, B, HID, HID);
    k_bnbin<<<B * HID / 16 / 256, 256, 0, stream>>>(C, pa, pb, Abuf, B * HID / 16, HID - 1);

    // ---- layer 2 ----
    hipMemsetAsync(gsum, 0, HID * 12, stream);
    k_gemm256<<<nbx * nby, 512, 0, stream>>>(Abuf, W2, C, gsum, gsq, HID, HID, nbx);
    k_finalize<<<HID / 128, 128, 0, stream>>>(gsum, gsq, g2, b2, pa, pb, B, HID, HID);
    k_bnbin<<<B * HID / 16 / 256, 256, 0, stream>>>(C, pa, pb, Abuf, B * HID / 16, HID - 1);

    // ---- layer 3 ----
    hipMemsetAsync(gsum, 0, HID * 12, stream);
    k_gemm256<<<nbx * nby, 512, 0, stream>>>(Abuf, W3, C, gsum, gsq, HID, HID, nbx);
    k_finalize<<<HID / 128, 128, 0, stream>>>(gsum, gsq, g3, b3, pa, pb, B, HID, HID);
    k_bnbin<<<B * HID / 16 / 256, 256, 0, stream>>>(C, pa, pb, Abuf, B * HID / 16, HID - 1);

    // ---- layer 4 (split-K, int32 atomics) ----
    hipMemsetAsync(C4, 0, (size_t)B * 16 * 4, stream);
    k_gemm4<<<dim3(B / 128, 8), 256, 0, stream>>>(Abuf, W4p, C4, HID);
    hipMemsetAsync(gsum, 0, HID * 12, stream);
    k_colstats4<<<16, 256, 0, stream>>>(C4, B, gsum, gsq);
    k_finalize<<<1, 128, 0, stream>>>(gsum, gsq, g4, b4, pa, pb, B, 10, 16);
    k_logsoftmax<<<B / 256, 256, 0, stream>>>(C4, pa, pb, out, B);
}